// Round 3
// baseline (423.383 us; speedup 1.0000x reference)
//
#include <hip/hip_runtime.h>
#include <stdint.h>

typedef unsigned long long u64;
typedef __attribute__((ext_vector_type(8))) short bf16x8;
typedef __attribute__((ext_vector_type(4))) float f32x4;
typedef __attribute__((ext_vector_type(4))) unsigned u32x4;

#define BATCH 512
#define FEAT 256
#define ENC 2048
#define HID 4096
#define CLS 1000
#define KTOT 12288      // 3 * 4096
#define NSPLIT 16
#define KSPLIT 768
#define PARTLD 1024

// ws offsets (enc2 region retired; counters live at its start)
#define OFF_CNT    0
#define OFF_ACT2   131072
#define OFF_TABLE  917504
#define OFF_SGN    1703936      // {negbits,validbits} u32 pairs per neuron
#define OFF_WT     2097152
#define OFF_PART   27262976
#define PART_BYTES (16ull * 512 * 1024 * 4)
#define WS_NEED    (OFF_PART + PART_BYTES)

// ---------- fp32 -> bf16 RNE ----------
static __device__ inline unsigned short f2bf(float f) {
    unsigned u = __float_as_uint(f);
    return (unsigned short)((u + 0x7FFFu + ((u >> 16) & 1u)) >> 16);
}

// ---------- async global->LDS, 16B/lane ----------
static __device__ inline void gld16(const void* g, void* s) {
    __builtin_amdgcn_global_load_lds((const __attribute__((address_space(1))) void*)g,
                                     (__attribute__((address_space(3))) void*)s, 16, 0, 0);
}

// ================= kernel 1: fused prep = scan | twt =================
// blocks [0,5120): scan   [5120,8192): twt
__global__ void __launch_bounds__(256)
k_prep(const float* __restrict__ W0, const float* __restrict__ W1,
       const float* __restrict__ W2,
       uint16_t* __restrict__ table, unsigned* __restrict__ bits,
       const float* __restrict__ out_w, short* __restrict__ wt) {
    __shared__ short tile[64 * 68];
    __shared__ int cnt4[4];
    __shared__ int lneg[4];
    int bid = blockIdx.x;
    int t = threadIdx.x;
    int lane = t & 63;
    int wv = t >> 6;

    if (bid < 5120) {
        // ---- scan: nontemporal streaming; col table + per-neuron bitmasks ----
        int wsid = bid * 4 + wv;
        int row, base, cidx;
        if (wsid < HID) { row = wsid; base = 0; cidx = wv; }
        else {
            int w2 = wsid - HID;
            row = HID + (w2 >> 1);
            base = (w2 & 1) * 2048;
            cidx = wv >> 1;
        }
        uint16_t* te = table + (size_t)row * 32;
        // zero-pad col row (redundant across waves sharing a row: benign, same value)
        if (lane < 8) ((u64*)te)[lane] = 0;
        if (t < 4) { cnt4[t] = 0; lneg[t] = 0; }
        __syncthreads();
        const float* Wr;
        if (row < HID)          Wr = W0 + (size_t)row * ENC;
        else if (row < 2 * HID) Wr = W1 + (size_t)(row - HID) * HID + base;
        else                    Wr = W2 + (size_t)(row - 2 * HID) * HID + base;
        const u32x4* p4 = (const u32x4*)Wr;
        u32x4 v[8];
        #pragma unroll
        for (int j = 0; j < 8; ++j) v[j] = __builtin_nontemporal_load(p4 + j * 64 + lane);
        #pragma unroll
        for (int j = 0; j < 8; ++j) {
            unsigned a0 = v[j].x, a1 = v[j].y, a2 = v[j].z, a3 = v[j].w;
            if (a0 | a1 | a2 | a3) {
                int col0 = base + j * 256 + lane * 4;
                if (a0) { int s = atomicAdd(&cnt4[cidx], 1); te[s] = (uint16_t)col0;
                          if (a0 >> 31) atomicOr(&lneg[cidx], (int)(1u << s)); }
                if (a1) { int s = atomicAdd(&cnt4[cidx], 1); te[s] = (uint16_t)(col0 + 1);
                          if (a1 >> 31) atomicOr(&lneg[cidx], (int)(1u << s)); }
                if (a2) { int s = atomicAdd(&cnt4[cidx], 1); te[s] = (uint16_t)(col0 + 2);
                          if (a2 >> 31) atomicOr(&lneg[cidx], (int)(1u << s)); }
                if (a3) { int s = atomicAdd(&cnt4[cidx], 1); te[s] = (uint16_t)(col0 + 3);
                          if (a3 >> 31) atomicOr(&lneg[cidx], (int)(1u << s)); }
            }
        }
        __syncthreads();
        if (lane == 0) {
            // waves paired on one row (W1/W2 halves) write identical values: benign
            int cnt = cnt4[cidx];
            unsigned nb = (unsigned)lneg[cidx];
            unsigned vb = (cnt >= 32) ? 0xFFFFFFFFu : ((1u << cnt) - 1u);
            uint2 pr; pr.x = nb; pr.y = vb;
            *(uint2*)(bits + (size_t)row * 2) = pr;
        }
        return;
    }
    {
        // ---- twt: transpose+convert out_w -> wt bf16 (swizzled) ----
        int b2 = bid - 5120;
        int kt = b2 % 192, ct = b2 / 192;
        int k0 = kt * 64, c0 = ct * 64;
        {
            int rrow = t >> 4, c4 = t & 15;
            int c = c0 + c4 * 4;
            #pragma unroll
            for (int rd = 0; rd < 4; ++rd) {
                int kl = rd * 16 + rrow;
                f32x4 vv;
                if (c < CLS)
                    vv = __builtin_nontemporal_load(
                        (const f32x4*)&out_w[(size_t)(k0 + kl) * CLS + c]);
                else { vv.x = 0.0f; vv.y = 0.0f; vv.z = 0.0f; vv.w = 0.0f; }
                short* d = &tile[kl * 68 + c4 * 4];
                d[0] = (short)f2bf(vv.x); d[1] = (short)f2bf(vv.y);
                d[2] = (short)f2bf(vv.z); d[3] = (short)f2bf(vv.w);
            }
        }
        __syncthreads();
        {
            int chunk = t & 7, cl2 = t >> 3;
            #pragma unroll
            for (int rd = 0; rd < 2; ++rd) {
                int c_local = rd * 32 + cl2;
                int c = c0 + c_local;
                unsigned s8[8];
                #pragma unroll
                for (int j = 0; j < 8; ++j)
                    s8[j] = (unsigned)(unsigned short)tile[(chunk * 8 + j) * 68 + c_local];
                uint4 pk;
                pk.x = s8[0] | (s8[1] << 16);
                pk.y = s8[2] | (s8[3] << 16);
                pk.z = s8[4] | (s8[5] << 16);
                pk.w = s8[6] | (s8[7] << 16);
                *(uint4*)&wt[(size_t)c * KTOT + k0 + ((chunk ^ (c & 7)) * 8)] = pk;
            }
        }
    }
}

// ================= bit-sliced CSA unit: 64 neurons x 64 samples, one lane each =========
// prow may point to LDS (inlined -> ds_read) or global. Returns fire-mask u64.
static __device__ __forceinline__ u64 unit_csa(
    const u64* __restrict__ prow,
    const uint16_t* __restrict__ table_l, const unsigned* __restrict__ bits_l, int n) {
    const uint4* tq = (const uint4*)(table_l + (size_t)n * 32);
    uint4 cwa[4] = {tq[0], tq[1], tq[2], tq[3]};
    uint2 bv = *(const uint2*)(bits_l + (size_t)n * 2);
    unsigned negb = bv.x, valb = bv.y;

    u64 P[4][4];
    #pragma unroll
    for (int k = 0; k < 4; ++k) {
        unsigned w0 = cwa[k].x, w1 = cwa[k].y, w2 = cwa[k].z, w3 = cwa[k].w;
        unsigned cc[8] = { w0 & 0xFFFFu, w0 >> 16, w1 & 0xFFFFu, w1 >> 16,
                           w2 & 0xFFFFu, w2 >> 16, w3 & 0xFFFFu, w3 >> 16 };
        u64 u[8];
        #pragma unroll
        for (int e = 0; e < 8; ++e) {
            int j = (k << 3) + e;
            u64 w = prow[cc[e]];
            u64 negm = 0ull - (u64)((negb >> j) & 1u);
            u64 vm   = 0ull - (u64)((valb >> j) & 1u);
            u[e] = (w ^ negm) & vm;
        }
        u64 s0, c0, s1, c1, s2, c2, b0, c3, t2, d0, b1, d1;
        { u64 t = u[0] ^ u[1]; s0 = t ^ u[2]; c0 = (u[0] & u[1]) | (u[2] & t); }
        { u64 t = u[3] ^ u[4]; s1 = t ^ u[5]; c1 = (u[3] & u[4]) | (u[5] & t); }
        s2 = u[6] ^ u[7]; c2 = u[6] & u[7];
        { u64 t = s0 ^ s1; b0 = t ^ s2; c3 = (s0 & s1) | (s2 & t); }
        { u64 t = c0 ^ c1; t2 = t ^ c2; d0 = (c0 & c1) | (c2 & t); }
        b1 = t2 ^ c3; d1 = t2 & c3;
        P[k][0] = b0; P[k][1] = b1; P[k][2] = d0 ^ d1; P[k][3] = d0 & d1;
    }
    u64 A[5], B[5], U[6];
    { u64 c;
      { u64 t = P[0][0] ^ P[1][0]; A[0] = t; c = P[0][0] & P[1][0]; }
      #pragma unroll
      for (int i = 1; i < 4; ++i) {
          u64 t = P[0][i] ^ P[1][i]; A[i] = t ^ c; c = (P[0][i] & P[1][i]) | (c & t); }
      A[4] = c; }
    { u64 c;
      { u64 t = P[2][0] ^ P[3][0]; B[0] = t; c = P[2][0] & P[3][0]; }
      #pragma unroll
      for (int i = 1; i < 4; ++i) {
          u64 t = P[2][i] ^ P[3][i]; B[i] = t ^ c; c = (P[2][i] & P[3][i]) | (c & t); }
      B[4] = c; }
    { u64 c;
      { u64 t = A[0] ^ B[0]; U[0] = t; c = A[0] & B[0]; }
      #pragma unroll
      for (int i = 1; i < 5; ++i) {
          u64 t = A[i] ^ B[i]; U[i] = t ^ c; c = (A[i] & B[i]) | (c & t); }
      U[5] = c; }
    int K = 60 - __popc(negb & valb);
    u64 c = 0;
    #pragma unroll
    for (int i = 0; i < 6; ++i) {
        u64 ki = 0ull - (u64)((K >> i) & 1);
        u64 t = U[i] ^ ki;
        c = (U[i] & ki) | (c & t);
    }
    return c;
}

// ================= kernel 2: encode + 3 layers, one block per batch-group =============
// 8 blocks x 1024 threads. Whole per-bg chain is LDS-resident; only block-level syncs.
__global__ void __launch_bounds__(1024)
k_net2(const float* __restrict__ x,
       const uint16_t* __restrict__ table, const unsigned* __restrict__ bits,
       u64* __restrict__ act2, int* __restrict__ cnt) {
    __shared__ u64 bufA[4096];
    __shared__ u64 bufB[4096];
    int bg = blockIdx.x;
    int tid = threadIdx.x, w = tid >> 6, lane = tid & 63;

    if (bg == 0 && tid < 64) cnt[tid] = 0;   // zero split-K arrival counters

    // ---- encode: wave w covers feats [w*16, w*16+16); lane = sample ----
    {
        const f32x4* xr = (const f32x4*)(x + (size_t)(bg * 64 + lane) * FEAT + w * 16);
        f32x4 xv[4] = {xr[0], xr[1], xr[2], xr[3]};
        #pragma unroll
        for (int ff = 0; ff < 16; ++ff) {
            float v = xv[ff >> 2][ff & 3];
            v = fminf(fmaxf(v, 0.0f), 1.0f);
            int lev = (int)rintf(v * 255.0f);            // RNE == jnp.round
            unsigned gray = (unsigned)(lev ^ (lev >> 1));
            u64 keep = 0;
            #pragma unroll
            for (int bit = 0; bit < 8; ++bit) {
                u64 m = __ballot((gray >> bit) & 1u);
                if (lane == bit) keep = m;
            }
            if (lane < 8) bufA[(w * 16 + ff) * 8 + lane] = keep;
        }
    }
    __syncthreads();

    // ---- layer 1: bufA(enc, 2048 words) -> bufB + global ----
    {
        u64* outG = act2 + (size_t)bg * HID;
        #pragma unroll
        for (int i = 0; i < 4; ++i) {
            int n = (w + i * 16) * 64 + lane;
            u64 c = unit_csa(bufA, table, bits, n);
            bufB[n] = c; outG[n] = c;
        }
    }
    __syncthreads();
    // ---- layer 2: bufB -> bufA + global ----
    {
        u64* outG = act2 + (size_t)(8 + bg) * HID;
        const uint16_t* tl = table + (size_t)HID * 32;
        const unsigned* bl = bits + (size_t)HID * 2;
        #pragma unroll
        for (int i = 0; i < 4; ++i) {
            int n = (w + i * 16) * 64 + lane;
            u64 c = unit_csa(bufB, tl, bl, n);
            bufA[n] = c; outG[n] = c;
        }
    }
    __syncthreads();
    // ---- layer 3: bufA -> global only ----
    {
        u64* outG = act2 + (size_t)(16 + bg) * HID;
        const uint16_t* tl = table + (size_t)2 * HID * 32;
        const unsigned* bl = bits + (size_t)2 * HID * 2;
        #pragma unroll
        for (int i = 0; i < 4; ++i) {
            int n = (w + i * 16) * 64 + lane;
            u64 c = unit_csa(bufA, tl, bl, n);
            outG[n] = c;
        }
    }
}

// ================= GEMM core (partial stores), parameterized tile ids =================
static __device__ __forceinline__ void gemm_core(
    const u64* __restrict__ act2, const short* __restrict__ wt,
    float* __restrict__ part, short* As, short* Bs,
    int mt, int nt, int ks, int tid) {
    int lane = tid & 63;
    int wv = tid >> 6, waveM = wv & 1, waveN = wv >> 1;
    int quad = lane >> 4, cl = lane & 15;
    f32x4 acc[4][4] = {};
    const char* Bb = (const char*)(wt + (size_t)nt * 128 * KTOT + ks * KSPLIT);
    int r = tid >> 3, sub = tid & 7;
    for (int kk = 0; kk < KSPLIT; kk += 64) {
        #pragma unroll
        for (int rd = 0; rd < 4; ++rd) {
            size_t go = (size_t)(r + rd * 32) * (KTOT * 2) + kk * 2 + sub * 16;
            gld16(Bb + go, &Bs[(tid + rd * 256) * 8]);
        }
        {
            int kabs = ks * KSPLIT + kk;
            int l = kabs >> 12, nk = kabs & 4095;
            #pragma unroll
            for (int i = 0; i < 4; ++i) {
                int item = i * 256 + tid;
                int rr = item >> 3, gg = item & 7;
                const u64* w8 = act2 + ((size_t)(l * 8 + mt * 2 + (rr >> 6))) * HID + nk + gg * 8;
                int bl = rr & 63;
                unsigned sh[8];
                #pragma unroll
                for (int j = 0; j < 8; ++j)
                    sh[j] = (unsigned)((w8[j] >> bl) & 1ull) * 0x3F80u;
                uint4 pk;
                pk.x = sh[0] | (sh[1] << 16);
                pk.y = sh[2] | (sh[3] << 16);
                pk.z = sh[4] | (sh[5] << 16);
                pk.w = sh[6] | (sh[7] << 16);
                *(uint4*)&As[rr * 64 + ((gg ^ (rr & 7)) * 8)] = pk;
            }
        }
        __syncthreads();
        #pragma unroll
        for (int s = 0; s < 2; ++s) {
            int xr = ((s * 4 + quad) ^ (cl & 7)) * 8;
            bf16x8 af[4], bfr[4];
            #pragma unroll
            for (int mf = 0; mf < 4; ++mf)
                af[mf] = *(const bf16x8*)&As[(waveM * 64 + mf * 16 + cl) * 64 + xr];
            #pragma unroll
            for (int nf = 0; nf < 4; ++nf)
                bfr[nf] = *(const bf16x8*)&Bs[(waveN * 64 + nf * 16 + cl) * 64 + xr];
            #pragma unroll
            for (int mf = 0; mf < 4; ++mf)
                #pragma unroll
                for (int nf = 0; nf < 4; ++nf)
                    acc[mf][nf] = __builtin_amdgcn_mfma_f32_16x16x32_bf16(
                        af[mf], bfr[nf], acc[mf][nf], 0, 0, 0);
        }
        __syncthreads();
    }
    float* pbase = part + (size_t)ks * (BATCH * PARTLD);
    #pragma unroll
    for (int mf = 0; mf < 4; ++mf)
        #pragma unroll
        for (int nf = 0; nf < 4; ++nf) {
            int cp = nt * 128 + waveN * 64 + nf * 16 + cl;
            #pragma unroll
            for (int rr = 0; rr < 4; ++rr) {
                int mg = mt * 128 + waveM * 64 + mf * 16 + quad * 4 + rr;
                pbase[(size_t)mg * PARTLD + cp] = acc[mf][nf][rr];
            }
        }
}

// ================= kernel 3: GEMM + fused split-K fixup reduction =====================
// XCD-grouped decode: nt = bid&7 -> all 64 blocks sharing a 3.1MB wt panel (and all 16
// ks-splits of each (mt,nt) tile) live on one XCD's L2. Last-arriving block per (mt,nt)
// reduces its tile from L2-local partials.
__global__ void __launch_bounds__(256)
k_gemm3(const u64* __restrict__ act2, const short* __restrict__ wt,
        float* __restrict__ out, float* __restrict__ part, int* __restrict__ cnt) {
    __shared__ __attribute__((aligned(16))) short As[128 * 64];
    __shared__ __attribute__((aligned(16))) short Bs[128 * 64];
    __shared__ int amlast;
    int bid = blockIdx.x;
    int nt = bid & 7, ks = (bid >> 3) & 15, mt = bid >> 7;
    int tid = threadIdx.x;
    gemm_core(act2, wt, part, As, Bs, mt, nt, ks, tid);
    __threadfence();
    if (tid == 0) amlast = (atomicAdd(&cnt[mt * 8 + nt], 1) == NSPLIT - 1) ? 1 : 0;
    __syncthreads();
    if (!amlast) return;
    // reduce the (mt,nt) 128x128 tile: thread t -> row r=t>>1, col-half ch=(t&1)*64
    int r = tid >> 1, ch = (tid & 1) * 64;
    int mg = mt * 128 + r;
    const float* pb = part + (size_t)mg * PARTLD + nt * 128 + ch;
    #pragma unroll
    for (int c4 = 0; c4 < 16; ++c4) {
        int cp = nt * 128 + ch + c4 * 4;
        if (cp < CLS) {
            f32x4 s = {0.f, 0.f, 0.f, 0.f};
            #pragma unroll
            for (int sp = 0; sp < NSPLIT; ++sp) {
                f32x4 v = *(const f32x4*)&pb[(size_t)sp * (BATCH * PARTLD) + c4 * 4];
                s.x += v.x; s.y += v.y; s.z += v.z; s.w += v.w;
            }
            *(f32x4*)&out[(size_t)mg * CLS + cp] = s;
        }
    }
}

// ================= fallback kernel (no-workspace path): atomic GEMM ===================
__global__ void __launch_bounds__(256)
k_gemm_atomic(const u64* __restrict__ act2, const short* __restrict__ wt,
              float* __restrict__ out) {
    __shared__ __attribute__((aligned(16))) short As[128 * 64];
    __shared__ __attribute__((aligned(16))) short Bs[128 * 64];
    int bid = blockIdx.x;
    int mt = bid & 3, nt = (bid >> 2) & 7, ks = bid >> 5;
    int tid = threadIdx.x, lane = tid & 63;
    int wv = tid >> 6, waveM = wv & 1, waveN = wv >> 1;
    int quad = lane >> 4, cl = lane & 15;
    f32x4 acc[4][4] = {};
    const char* Bb = (const char*)(wt + (size_t)nt * 128 * KTOT + ks * KSPLIT);
    int r = tid >> 3, sub = tid & 7;
    for (int kk = 0; kk < KSPLIT; kk += 64) {
        #pragma unroll
        for (int rd = 0; rd < 4; ++rd) {
            size_t go = (size_t)(r + rd * 32) * (KTOT * 2) + kk * 2 + sub * 16;
            gld16(Bb + go, &Bs[(tid + rd * 256) * 8]);
        }
        {
            int kabs = ks * KSPLIT + kk;
            int l = kabs >> 12, nk = kabs & 4095;
            #pragma unroll
            for (int i = 0; i < 4; ++i) {
                int item = i * 256 + tid;
                int rr = item >> 3, gg = item & 7;
                const u64* w8 = act2 + ((size_t)(l * 8 + mt * 2 + (rr >> 6))) * HID + nk + gg * 8;
                int bl = rr & 63;
                unsigned sh[8];
                #pragma unroll
                for (int j = 0; j < 8; ++j)
                    sh[j] = (unsigned)((w8[j] >> bl) & 1ull) * 0x3F80u;
                uint4 pk;
                pk.x = sh[0] | (sh[1] << 16);
                pk.y = sh[2] | (sh[3] << 16);
                pk.z = sh[4] | (sh[5] << 16);
                pk.w = sh[6] | (sh[7] << 16);
                *(uint4*)&As[rr * 64 + ((gg ^ (rr & 7)) * 8)] = pk;
            }
        }
        __syncthreads();
        #pragma unroll
        for (int s = 0; s < 2; ++s) {
            int xr = ((s * 4 + quad) ^ (cl & 7)) * 8;
            bf16x8 af[4], bfr[4];
            #pragma unroll
            for (int mf = 0; mf < 4; ++mf)
                af[mf] = *(const bf16x8*)&As[(waveM * 64 + mf * 16 + cl) * 64 + xr];
            #pragma unroll
            for (int nf = 0; nf < 4; ++nf)
                bfr[nf] = *(const bf16x8*)&Bs[(waveN * 64 + nf * 16 + cl) * 64 + xr];
            #pragma unroll
            for (int mf = 0; mf < 4; ++mf)
                #pragma unroll
                for (int nf = 0; nf < 4; ++nf)
                    acc[mf][nf] = __builtin_amdgcn_mfma_f32_16x16x32_bf16(
                        af[mf], bfr[nf], acc[mf][nf], 0, 0, 0);
        }
        __syncthreads();
    }
    #pragma unroll
    for (int mf = 0; mf < 4; ++mf)
        #pragma unroll
        for (int nf = 0; nf < 4; ++nf) {
            int cp = nt * 128 + waveN * 64 + nf * 16 + cl;
            if (cp < CLS) {
                #pragma unroll
                for (int rr = 0; rr < 4; ++rr) {
                    int mg = mt * 128 + waveM * 64 + mf * 16 + quad * 4 + rr;
                    atomicAdd(&out[(size_t)mg * CLS + cp], acc[mf][nf][rr]);
                }
            }
        }
}

extern "C" void kernel_launch(void* const* d_in, const int* in_sizes, int n_in,
                              void* d_out, int out_size, void* d_ws, size_t ws_size,
                              hipStream_t stream) {
    const float* x     = (const float*)d_in[0];
    const float* W0    = (const float*)d_in[1];
    const float* W1    = (const float*)d_in[2];
    const float* W2    = (const float*)d_in[3];
    const float* out_w = (const float*)d_in[4];
    float* out = (float*)d_out;
    char* ws = (char*)d_ws;

    int*            cnt    = (int*)(ws + OFF_CNT);
    u64*            act2   = (u64*)(ws + OFF_ACT2);
    uint16_t*       table  = (uint16_t*)(ws + OFF_TABLE);
    unsigned*       bits   = (unsigned*)(ws + OFF_SGN);
    short*          wt     = (short*)(ws + OFF_WT);
    float*          part   = (float*)(ws + OFF_PART);

    int use_part = (ws_size >= (size_t)WS_NEED) ? 1 : 0;

    hipLaunchKernelGGL(k_prep, dim3(8192), dim3(256), 0, stream,
                       W0, W1, W2, table, bits, out_w, wt);
    hipLaunchKernelGGL(k_net2, dim3(8), dim3(1024), 0, stream,
                       x, table, bits, act2, cnt);
    if (use_part) {
        hipLaunchKernelGGL(k_gemm3, dim3(512), dim3(256), 0, stream,
                           act2, wt, out, part, cnt);
    } else {
        (void)hipMemsetAsync(d_out, 0, (size_t)BATCH * CLS * sizeof(float), stream);
        hipLaunchKernelGGL(k_gemm_atomic, dim3(512), dim3(256), 0, stream,
                           act2, wt, out);
    }
}

// Round 4
// 404.611 us; speedup vs baseline: 1.0464x; 1.0464x over previous
//
#include <hip/hip_runtime.h>
#include <stdint.h>

typedef unsigned long long u64;
typedef __attribute__((ext_vector_type(8))) short bf16x8;
typedef __attribute__((ext_vector_type(4))) float f32x4;
typedef __attribute__((ext_vector_type(4))) unsigned u32x4;

#define BATCH 512
#define FEAT 256
#define ENC 2048
#define HID 4096
#define CLS 1000
#define KTOT 12288      // 3 * 4096
#define NSPLIT 16
#define KSPLIT 768
#define PARTLD 1024

// ws offsets
#define OFF_ENC2   0
#define OFF_ACT2   131072
#define OFF_TABLE  917504
#define OFF_SGN    1703936      // {negbits,validbits} u32 pairs per neuron
#define OFF_CNT    1802240      // 64 ints: [0..7] L1-done, [8..15] L2-done, [16..47] gemm tiles
#define OFF_WT     2097152
#define OFF_PART   27262976
#define PART_BYTES (16ull * 512 * 1024 * 4)
#define WS_NEED    (OFF_PART + PART_BYTES)

// ---------- fp32 -> bf16 RNE ----------
static __device__ inline unsigned short f2bf(float f) {
    unsigned u = __float_as_uint(f);
    return (unsigned short)((u + 0x7FFFu + ((u >> 16) & 1u)) >> 16);
}

// ---------- async global->LDS, 16B/lane ----------
static __device__ inline void gld16(const void* g, void* s) {
    __builtin_amdgcn_global_load_lds((const __attribute__((address_space(1))) void*)g,
                                     (__attribute__((address_space(3))) void*)s, 16, 0, 0);
}

// ================= kernel 1: fused prep = encode | scan | twt =================
// blocks [0,512): encode   [512,5632): scan   [5632,8704): twt
__global__ void __launch_bounds__(256)
k_prep(const float* __restrict__ x, u64* __restrict__ enc2,
       const float* __restrict__ W0, const float* __restrict__ W1,
       const float* __restrict__ W2,
       uint16_t* __restrict__ table, unsigned* __restrict__ bits,
       const float* __restrict__ out_w, short* __restrict__ wt,
       int* __restrict__ sync) {
    __shared__ short tile[64 * 68];
    __shared__ int cnt4[4];
    __shared__ int lneg[4];
    int bid = blockIdx.x;
    int t = threadIdx.x;
    int lane = t & 63;
    int wv = t >> 6;

    if (bid < 512) {
        if (bid == 0 && t < 64) sync[t] = 0;             // zero all sync counters
        int wid = bid * 4 + wv;
        int f = wid >> 3, bg = wid & 7;
        float v = x[(size_t)(bg * 64 + lane) * FEAT + f];
        v = fminf(fmaxf(v, 0.0f), 1.0f);
        int lev = (int)rintf(v * 255.0f);                // RNE == jnp.round
        unsigned gray = (unsigned)(lev ^ (lev >> 1));
        u64 w = 0;
        #pragma unroll
        for (int bit = 0; bit < 8; ++bit) {
            u64 m = __ballot((gray >> bit) & 1u);
            if (lane == bit) w = m;
        }
        if (lane < 8) enc2[(size_t)bg * ENC + f * 8 + lane] = w;
        return;
    }
    if (bid < 5632) {
        // ---- scan: nontemporal streaming; col table + per-neuron bitmasks ----
        int wsid = (bid - 512) * 4 + wv;
        int row, base, cidx;
        if (wsid < HID) { row = wsid; base = 0; cidx = wv; }
        else {
            int w2 = wsid - HID;
            row = HID + (w2 >> 1);
            base = (w2 & 1) * 2048;
            cidx = wv >> 1;
        }
        uint16_t* te = table + (size_t)row * 32;
        // zero-pad col row (redundant across waves sharing a row: benign, same value)
        if (lane < 8) ((u64*)te)[lane] = 0;
        if (t < 4) { cnt4[t] = 0; lneg[t] = 0; }
        __syncthreads();
        const float* Wr;
        if (row < HID)          Wr = W0 + (size_t)row * ENC;
        else if (row < 2 * HID) Wr = W1 + (size_t)(row - HID) * HID + base;
        else                    Wr = W2 + (size_t)(row - 2 * HID) * HID + base;
        const u32x4* p4 = (const u32x4*)Wr;
        u32x4 v[8];
        #pragma unroll
        for (int j = 0; j < 8; ++j) v[j] = __builtin_nontemporal_load(p4 + j * 64 + lane);
        #pragma unroll
        for (int j = 0; j < 8; ++j) {
            unsigned a0 = v[j].x, a1 = v[j].y, a2 = v[j].z, a3 = v[j].w;
            if (a0 | a1 | a2 | a3) {
                int col0 = base + j * 256 + lane * 4;
                if (a0) { int s = atomicAdd(&cnt4[cidx], 1); te[s] = (uint16_t)col0;
                          if (a0 >> 31) atomicOr(&lneg[cidx], (int)(1u << s)); }
                if (a1) { int s = atomicAdd(&cnt4[cidx], 1); te[s] = (uint16_t)(col0 + 1);
                          if (a1 >> 31) atomicOr(&lneg[cidx], (int)(1u << s)); }
                if (a2) { int s = atomicAdd(&cnt4[cidx], 1); te[s] = (uint16_t)(col0 + 2);
                          if (a2 >> 31) atomicOr(&lneg[cidx], (int)(1u << s)); }
                if (a3) { int s = atomicAdd(&cnt4[cidx], 1); te[s] = (uint16_t)(col0 + 3);
                          if (a3 >> 31) atomicOr(&lneg[cidx], (int)(1u << s)); }
            }
        }
        __syncthreads();
        if (lane == 0) {
            // waves paired on one row (W1/W2 halves) write identical values: benign
            int cnt = cnt4[cidx];
            unsigned nb = (unsigned)lneg[cidx];
            unsigned vb = (cnt >= 32) ? 0xFFFFFFFFu : ((1u << cnt) - 1u);
            uint2 pr; pr.x = nb; pr.y = vb;
            *(uint2*)(bits + (size_t)row * 2) = pr;
        }
        return;
    }
    {
        // ---- twt: transpose+convert out_w -> wt bf16 (swizzled) ----
        int b2 = bid - 5632;
        int kt = b2 % 192, ct = b2 / 192;
        int k0 = kt * 64, c0 = ct * 64;
        {
            int rrow = t >> 4, c4 = t & 15;
            int c = c0 + c4 * 4;
            #pragma unroll
            for (int rd = 0; rd < 4; ++rd) {
                int kl = rd * 16 + rrow;
                f32x4 vv;
                if (c < CLS)
                    vv = __builtin_nontemporal_load(
                        (const f32x4*)&out_w[(size_t)(k0 + kl) * CLS + c]);
                else { vv.x = 0.0f; vv.y = 0.0f; vv.z = 0.0f; vv.w = 0.0f; }
                short* d = &tile[kl * 68 + c4 * 4];
                d[0] = (short)f2bf(vv.x); d[1] = (short)f2bf(vv.y);
                d[2] = (short)f2bf(vv.z); d[3] = (short)f2bf(vv.w);
            }
        }
        __syncthreads();
        {
            int chunk = t & 7, cl2 = t >> 3;
            #pragma unroll
            for (int rd = 0; rd < 2; ++rd) {
                int c_local = rd * 32 + cl2;
                int c = c0 + c_local;
                unsigned s8[8];
                #pragma unroll
                for (int j = 0; j < 8; ++j)
                    s8[j] = (unsigned)(unsigned short)tile[(chunk * 8 + j) * 68 + c_local];
                uint4 pk;
                pk.x = s8[0] | (s8[1] << 16);
                pk.y = s8[2] | (s8[3] << 16);
                pk.z = s8[4] | (s8[5] << 16);
                pk.w = s8[6] | (s8[7] << 16);
                *(uint4*)&wt[(size_t)c * KTOT + k0 + ((chunk ^ (c & 7)) * 8)] = pk;
            }
        }
    }
}

// ================= bit-sliced CSA unit: 64 neurons x 64 samples, one lane each =========
static __device__ __forceinline__ u64 unit_csa(
    const u64* __restrict__ prow,
    const uint16_t* __restrict__ table_l, const unsigned* __restrict__ bits_l, int n) {
    const uint4* tq = (const uint4*)(table_l + (size_t)n * 32);
    uint4 cwa[4] = {tq[0], tq[1], tq[2], tq[3]};
    uint2 bv = *(const uint2*)(bits_l + (size_t)n * 2);
    unsigned negb = bv.x, valb = bv.y;

    u64 P[4][4];
    #pragma unroll
    for (int k = 0; k < 4; ++k) {
        unsigned w0 = cwa[k].x, w1 = cwa[k].y, w2 = cwa[k].z, w3 = cwa[k].w;
        unsigned cc[8] = { w0 & 0xFFFFu, w0 >> 16, w1 & 0xFFFFu, w1 >> 16,
                           w2 & 0xFFFFu, w2 >> 16, w3 & 0xFFFFu, w3 >> 16 };
        u64 u[8];
        #pragma unroll
        for (int e = 0; e < 8; ++e) {
            int j = (k << 3) + e;
            u64 w = prow[cc[e]];
            u64 negm = 0ull - (u64)((negb >> j) & 1u);
            u64 vm   = 0ull - (u64)((valb >> j) & 1u);
            u[e] = (w ^ negm) & vm;
        }
        u64 s0, c0, s1, c1, s2, c2, b0, c3, t2, d0, b1, d1;
        { u64 t = u[0] ^ u[1]; s0 = t ^ u[2]; c0 = (u[0] & u[1]) | (u[2] & t); }
        { u64 t = u[3] ^ u[4]; s1 = t ^ u[5]; c1 = (u[3] & u[4]) | (u[5] & t); }
        s2 = u[6] ^ u[7]; c2 = u[6] & u[7];
        { u64 t = s0 ^ s1; b0 = t ^ s2; c3 = (s0 & s1) | (s2 & t); }
        { u64 t = c0 ^ c1; t2 = t ^ c2; d0 = (c0 & c1) | (c2 & t); }
        b1 = t2 ^ c3; d1 = t2 & c3;
        P[k][0] = b0; P[k][1] = b1; P[k][2] = d0 ^ d1; P[k][3] = d0 & d1;
    }
    u64 A[5], B[5], U[6];
    { u64 c;
      { u64 t = P[0][0] ^ P[1][0]; A[0] = t; c = P[0][0] & P[1][0]; }
      #pragma unroll
      for (int i = 1; i < 4; ++i) {
          u64 t = P[0][i] ^ P[1][i]; A[i] = t ^ c; c = (P[0][i] & P[1][i]) | (c & t); }
      A[4] = c; }
    { u64 c;
      { u64 t = P[2][0] ^ P[3][0]; B[0] = t; c = P[2][0] & P[3][0]; }
      #pragma unroll
      for (int i = 1; i < 4; ++i) {
          u64 t = P[2][i] ^ P[3][i]; B[i] = t ^ c; c = (P[2][i] & P[3][i]) | (c & t); }
      B[4] = c; }
    { u64 c;
      { u64 t = A[0] ^ B[0]; U[0] = t; c = A[0] & B[0]; }
      #pragma unroll
      for (int i = 1; i < 5; ++i) {
          u64 t = A[i] ^ B[i]; U[i] = t ^ c; c = (A[i] & B[i]) | (c & t); }
      U[5] = c; }
    int K = 60 - __popc(negb & valb);
    u64 c = 0;
    #pragma unroll
    for (int i = 0; i < 6; ++i) {
        u64 ki = 0ull - (u64)((K >> i) & 1);
        u64 t = U[i] ^ ki;
        c = (U[i] & ki) | (c & t);
    }
    return c;
}

// ================= kernel 2: all 3 layers, 512 one-wave blocks, spin-synced ===========
// Block (g,bg) computes unit (g,bg) of each layer. Layer l+1 of bg depends only on
// layer l of the SAME bg -> per-bg arrival counter (64 blocks each). 512 zero-LDS
// one-wave blocks on 256 CUs are trivially co-resident (capacity >> grid).
__global__ void __launch_bounds__(64)
k_layers(const u64* __restrict__ enc2, const uint16_t* __restrict__ table,
         const unsigned* __restrict__ bits, u64* __restrict__ act2,
         int* __restrict__ sync) {
    int unit = blockIdx.x;
    int lane = threadIdx.x;
    int g = unit >> 3, bg = unit & 7;
    int n = (g << 6) + lane;

    // ---- layer 1: enc2[bg] -> act2[0][bg] ----
    u64 c = unit_csa(enc2 + (size_t)bg * ENC, table, bits, n);
    act2[(size_t)bg * HID + n] = c;
    __threadfence();
    if (lane == 0) {
        atomicAdd(&sync[bg], 1);
        while (atomicAdd(&sync[bg], 0) < 64) __builtin_amdgcn_s_sleep(8);
    }
    __syncthreads();
    __threadfence();
    // ---- layer 2: act2[0][bg] -> act2[1][bg] ----
    c = unit_csa(act2 + (size_t)bg * HID, table + (size_t)HID * 32,
                 bits + (size_t)HID * 2, n);
    act2[(size_t)(8 + bg) * HID + n] = c;
    __threadfence();
    if (lane == 0) {
        atomicAdd(&sync[8 + bg], 1);
        while (atomicAdd(&sync[8 + bg], 0) < 64) __builtin_amdgcn_s_sleep(8);
    }
    __syncthreads();
    __threadfence();
    // ---- layer 3: act2[1][bg] -> act2[2][bg] ----
    c = unit_csa(act2 + (size_t)(8 + bg) * HID, table + (size_t)2 * HID * 32,
                 bits + (size_t)2 * HID * 2, n);
    act2[(size_t)(16 + bg) * HID + n] = c;
}

// ================= GEMM core (partial stores), R1-proven decode =======================
static __device__ __forceinline__ void gemm_core(
    const u64* __restrict__ act2, const short* __restrict__ wt,
    float* __restrict__ part, short* As, short* Bs,
    int mt, int nt, int ks, int tid) {
    int lane = tid & 63;
    int wv = tid >> 6, waveM = wv & 1, waveN = wv >> 1;
    int quad = lane >> 4, cl = lane & 15;
    f32x4 acc[4][4] = {};
    const char* Bb = (const char*)(wt + (size_t)nt * 128 * KTOT + ks * KSPLIT);
    int r = tid >> 3, sub = tid & 7;
    for (int kk = 0; kk < KSPLIT; kk += 64) {
        #pragma unroll
        for (int rd = 0; rd < 4; ++rd) {
            size_t go = (size_t)(r + rd * 32) * (KTOT * 2) + kk * 2 + sub * 16;
            gld16(Bb + go, &Bs[(tid + rd * 256) * 8]);
        }
        {
            int kabs = ks * KSPLIT + kk;
            int l = kabs >> 12, nk = kabs & 4095;
            #pragma unroll
            for (int i = 0; i < 4; ++i) {
                int item = i * 256 + tid;
                int rr = item >> 3, gg = item & 7;
                const u64* w8 = act2 + ((size_t)(l * 8 + mt * 2 + (rr >> 6))) * HID + nk + gg * 8;
                int bl = rr & 63;
                unsigned sh[8];
                #pragma unroll
                for (int j = 0; j < 8; ++j)
                    sh[j] = (unsigned)((w8[j] >> bl) & 1ull) * 0x3F80u;
                uint4 pk;
                pk.x = sh[0] | (sh[1] << 16);
                pk.y = sh[2] | (sh[3] << 16);
                pk.z = sh[4] | (sh[5] << 16);
                pk.w = sh[6] | (sh[7] << 16);
                *(uint4*)&As[rr * 64 + ((gg ^ (rr & 7)) * 8)] = pk;
            }
        }
        __syncthreads();
        #pragma unroll
        for (int s = 0; s < 2; ++s) {
            int xr = ((s * 4 + quad) ^ (cl & 7)) * 8;
            bf16x8 af[4], bfr[4];
            #pragma unroll
            for (int mf = 0; mf < 4; ++mf)
                af[mf] = *(const bf16x8*)&As[(waveM * 64 + mf * 16 + cl) * 64 + xr];
            #pragma unroll
            for (int nf = 0; nf < 4; ++nf)
                bfr[nf] = *(const bf16x8*)&Bs[(waveN * 64 + nf * 16 + cl) * 64 + xr];
            #pragma unroll
            for (int mf = 0; mf < 4; ++mf)
                #pragma unroll
                for (int nf = 0; nf < 4; ++nf)
                    acc[mf][nf] = __builtin_amdgcn_mfma_f32_16x16x32_bf16(
                        af[mf], bfr[nf], acc[mf][nf], 0, 0, 0);
        }
        __syncthreads();
    }
    float* pbase = part + (size_t)ks * (BATCH * PARTLD);
    #pragma unroll
    for (int mf = 0; mf < 4; ++mf)
        #pragma unroll
        for (int nf = 0; nf < 4; ++nf) {
            int cp = nt * 128 + waveN * 64 + nf * 16 + cl;
            #pragma unroll
            for (int rr = 0; rr < 4; ++rr) {
                int mg = mt * 128 + waveM * 64 + mf * 16 + quad * 4 + rr;
                pbase[(size_t)mg * PARTLD + cp] = acc[mf][nf][rr];
            }
        }
}

// ================= kernel 3: GEMM + fused split-K fixup (L1-friendly loop order) ======
__global__ void __launch_bounds__(256)
k_gemm4(const u64* __restrict__ act2, const short* __restrict__ wt,
        float* __restrict__ out, float* __restrict__ part, int* __restrict__ cnt2) {
    __shared__ __attribute__((aligned(16))) short As[128 * 64];
    __shared__ __attribute__((aligned(16))) short Bs[128 * 64];
    __shared__ int amlast;
    int bid = blockIdx.x;
    int mt = bid & 3, nt = (bid >> 2) & 7, ks = bid >> 5;
    int tid = threadIdx.x;
    gemm_core(act2, wt, part, As, Bs, mt, nt, ks, tid);
    __threadfence();                                   // release partial stores
    if (tid == 0) amlast = (atomicAdd(&cnt2[nt * 4 + mt], 1) == NSPLIT - 1) ? 1 : 0;
    __syncthreads();
    if (!amlast) return;
    __threadfence();                                   // acquire others' partials
    // reduce the (mt,nt) 128x128 tile: sp-outer, c4-inner, register accumulators.
    // Per wave per sp: 64 x 128B lines (8 KB), each fully consumed by the c4 unroll.
    int r = tid >> 1, ch = (tid & 1) * 64;
    int mg = mt * 128 + r;
    const float* pb = part + (size_t)mg * PARTLD + nt * 128 + ch;
    f32x4 s[16];
    #pragma unroll
    for (int i = 0; i < 16; ++i) { s[i].x = 0.f; s[i].y = 0.f; s[i].z = 0.f; s[i].w = 0.f; }
    for (int sp = 0; sp < NSPLIT; ++sp) {
        const f32x4* p = (const f32x4*)(pb + (size_t)sp * (BATCH * PARTLD));
        #pragma unroll
        for (int c4 = 0; c4 < 16; ++c4) {
            f32x4 v = p[c4];
            s[c4].x += v.x; s[c4].y += v.y; s[c4].z += v.z; s[c4].w += v.w;
        }
    }
    #pragma unroll
    for (int c4 = 0; c4 < 16; ++c4) {
        int cp = nt * 128 + ch + c4 * 4;
        if (cp < CLS)
            *(f32x4*)&out[(size_t)mg * CLS + cp] = s[c4];
    }
}

// ================= fallback kernel (no-workspace path): atomic GEMM ===================
__global__ void __launch_bounds__(256)
k_gemm_atomic(const u64* __restrict__ act2, const short* __restrict__ wt,
              float* __restrict__ out) {
    __shared__ __attribute__((aligned(16))) short As[128 * 64];
    __shared__ __attribute__((aligned(16))) short Bs[128 * 64];
    int bid = blockIdx.x;
    int mt = bid & 3, nt = (bid >> 2) & 7, ks = bid >> 5;
    int tid = threadIdx.x, lane = tid & 63;
    int wv = tid >> 6, waveM = wv & 1, waveN = wv >> 1;
    int quad = lane >> 4, cl = lane & 15;
    f32x4 acc[4][4] = {};
    const char* Bb = (const char*)(wt + (size_t)nt * 128 * KTOT + ks * KSPLIT);
    int r = tid >> 3, sub = tid & 7;
    for (int kk = 0; kk < KSPLIT; kk += 64) {
        #pragma unroll
        for (int rd = 0; rd < 4; ++rd) {
            size_t go = (size_t)(r + rd * 32) * (KTOT * 2) + kk * 2 + sub * 16;
            gld16(Bb + go, &Bs[(tid + rd * 256) * 8]);
        }
        {
            int kabs = ks * KSPLIT + kk;
            int l = kabs >> 12, nk = kabs & 4095;
            #pragma unroll
            for (int i = 0; i < 4; ++i) {
                int item = i * 256 + tid;
                int rr = item >> 3, gg = item & 7;
                const u64* w8 = act2 + ((size_t)(l * 8 + mt * 2 + (rr >> 6))) * HID + nk + gg * 8;
                int bl = rr & 63;
                unsigned sh[8];
                #pragma unroll
                for (int j = 0; j < 8; ++j)
                    sh[j] = (unsigned)((w8[j] >> bl) & 1ull) * 0x3F80u;
                uint4 pk;
                pk.x = sh[0] | (sh[1] << 16);
                pk.y = sh[2] | (sh[3] << 16);
                pk.z = sh[4] | (sh[5] << 16);
                pk.w = sh[6] | (sh[7] << 16);
                *(uint4*)&As[rr * 64 + ((gg ^ (rr & 7)) * 8)] = pk;
            }
        }
        __syncthreads();
        #pragma unroll
        for (int s = 0; s < 2; ++s) {
            int xr = ((s * 4 + quad) ^ (cl & 7)) * 8;
            bf16x8 af[4], bfr[4];
            #pragma unroll
            for (int mf = 0; mf < 4; ++mf)
                af[mf] = *(const bf16x8*)&As[(waveM * 64 + mf * 16 + cl) * 64 + xr];
            #pragma unroll
            for (int nf = 0; nf < 4; ++nf)
                bfr[nf] = *(const bf16x8*)&Bs[(waveN * 64 + nf * 16 + cl) * 64 + xr];
            #pragma unroll
            for (int mf = 0; mf < 4; ++mf)
                #pragma unroll
                for (int nf = 0; nf < 4; ++nf)
                    acc[mf][nf] = __builtin_amdgcn_mfma_f32_16x16x32_bf16(
                        af[mf], bfr[nf], acc[mf][nf], 0, 0, 0);
        }
        __syncthreads();
    }
    #pragma unroll
    for (int mf = 0; mf < 4; ++mf)
        #pragma unroll
        for (int nf = 0; nf < 4; ++nf) {
            int cp = nt * 128 + waveN * 64 + nf * 16 + cl;
            if (cp < CLS) {
                #pragma unroll
                for (int rr = 0; rr < 4; ++rr) {
                    int mg = mt * 128 + waveM * 64 + mf * 16 + quad * 4 + rr;
                    atomicAdd(&out[(size_t)mg * CLS + cp], acc[mf][nf][rr]);
                }
            }
        }
}

extern "C" void kernel_launch(void* const* d_in, const int* in_sizes, int n_in,
                              void* d_out, int out_size, void* d_ws, size_t ws_size,
                              hipStream_t stream) {
    const float* x     = (const float*)d_in[0];
    const float* W0    = (const float*)d_in[1];
    const float* W1    = (const float*)d_in[2];
    const float* W2    = (const float*)d_in[3];
    const float* out_w = (const float*)d_in[4];
    float* out = (float*)d_out;
    char* ws = (char*)d_ws;

    u64*       enc2   = (u64*)(ws + OFF_ENC2);
    u64*       act2   = (u64*)(ws + OFF_ACT2);
    uint16_t*  table  = (uint16_t*)(ws + OFF_TABLE);
    unsigned*  bits   = (unsigned*)(ws + OFF_SGN);
    int*       sync   = (int*)(ws + OFF_CNT);
    short*     wt     = (short*)(ws + OFF_WT);
    float*     part   = (float*)(ws + OFF_PART);

    int use_part = (ws_size >= (size_t)WS_NEED) ? 1 : 0;

    hipLaunchKernelGGL(k_prep, dim3(8704), dim3(256), 0, stream,
                       x, enc2, W0, W1, W2, table, bits, out_w, wt, sync);
    hipLaunchKernelGGL(k_layers, dim3(512), dim3(64), 0, stream,
                       enc2, table, bits, act2, sync);
    if (use_part) {
        hipLaunchKernelGGL(k_gemm4, dim3(512), dim3(256), 0, stream,
                           act2, wt, out, part, sync + 16);
    } else {
        (void)hipMemsetAsync(d_out, 0, (size_t)BATCH * CLS * sizeof(float), stream);
        hipLaunchKernelGGL(k_gemm_atomic, dim3(512), dim3(256), 0, stream,
                           act2, wt, out);
    }
}

// Round 5
// 271.212 us; speedup vs baseline: 1.5611x; 1.4919x over previous
//
#include <hip/hip_runtime.h>
#include <stdint.h>

typedef unsigned long long u64;
typedef __attribute__((ext_vector_type(8))) short bf16x8;
typedef __attribute__((ext_vector_type(4))) float f32x4;
typedef __attribute__((ext_vector_type(4))) unsigned u32x4;

#define BATCH 512
#define FEAT 256
#define ENC 2048
#define HID 4096
#define CLS 1000
#define KTOT 12288      // 3 * 4096
#define KSPLIT 768

// ws offsets
#define OFF_ENC2   0
#define OFF_ACT2   131072
#define OFF_TABLE  917504
#define OFF_SGN    1703936      // {negbits,validbits} u32 pairs per neuron
#define OFF_WT     2097152

// ---------- fp32 -> bf16 RNE ----------
static __device__ inline unsigned short f2bf(float f) {
    unsigned u = __float_as_uint(f);
    return (unsigned short)((u + 0x7FFFu + ((u >> 16) & 1u)) >> 16);
}

// ---------- async global->LDS, 16B/lane ----------
static __device__ inline void gld16(const void* g, void* s) {
    __builtin_amdgcn_global_load_lds((const __attribute__((address_space(1))) void*)g,
                                     (__attribute__((address_space(3))) void*)s, 16, 0, 0);
}

// ================= kernel 1: fused prep = encode+zero | scan | twt =================
// blocks [0,512): encode + zero out   [512,5632): scan   [5632,8704): twt
__global__ void __launch_bounds__(256)
k_prep(const float* __restrict__ x, u64* __restrict__ enc2,
       const float* __restrict__ W0, const float* __restrict__ W1,
       const float* __restrict__ W2,
       uint16_t* __restrict__ table, unsigned* __restrict__ bits,
       const float* __restrict__ out_w, short* __restrict__ wt,
       float* __restrict__ out) {
    __shared__ short tile[64 * 68];
    __shared__ int cnt4[4];
    __shared__ int lneg[4];
    int bid = blockIdx.x;
    int t = threadIdx.x;
    int lane = t & 63;
    int wv = t >> 6;

    if (bid < 512) {
        // zero out (512*256 float4 slots cover the 128000 needed)
        int oidx = bid * 256 + t;
        if (oidx < (BATCH * CLS) / 4) {
            f32x4 z = {0.f, 0.f, 0.f, 0.f};
            *(f32x4*)&out[(size_t)oidx * 4] = z;
        }
        int wid = bid * 4 + wv;
        int f = wid >> 3, bg = wid & 7;
        float v = x[(size_t)(bg * 64 + lane) * FEAT + f];
        v = fminf(fmaxf(v, 0.0f), 1.0f);
        int lev = (int)rintf(v * 255.0f);                // RNE == jnp.round
        unsigned gray = (unsigned)(lev ^ (lev >> 1));
        u64 w = 0;
        #pragma unroll
        for (int bit = 0; bit < 8; ++bit) {
            u64 m = __ballot((gray >> bit) & 1u);
            if (lane == bit) w = m;
        }
        if (lane < 8) enc2[(size_t)bg * ENC + f * 8 + lane] = w;
        return;
    }
    if (bid < 5632) {
        // ---- scan: nontemporal streaming; col table + per-neuron bitmasks ----
        int wsid = (bid - 512) * 4 + wv;
        int row, base, cidx;
        if (wsid < HID) { row = wsid; base = 0; cidx = wv; }
        else {
            int w2 = wsid - HID;
            row = HID + (w2 >> 1);
            base = (w2 & 1) * 2048;
            cidx = wv >> 1;
        }
        uint16_t* te = table + (size_t)row * 32;
        // zero-pad col row (redundant across waves sharing a row: benign, same value)
        if (lane < 8) ((u64*)te)[lane] = 0;
        if (t < 4) { cnt4[t] = 0; lneg[t] = 0; }
        __syncthreads();
        const float* Wr;
        if (row < HID)          Wr = W0 + (size_t)row * ENC;
        else if (row < 2 * HID) Wr = W1 + (size_t)(row - HID) * HID + base;
        else                    Wr = W2 + (size_t)(row - 2 * HID) * HID + base;
        const u32x4* p4 = (const u32x4*)Wr;
        u32x4 v[8];
        #pragma unroll
        for (int j = 0; j < 8; ++j) v[j] = __builtin_nontemporal_load(p4 + j * 64 + lane);
        #pragma unroll
        for (int j = 0; j < 8; ++j) {
            unsigned a0 = v[j].x, a1 = v[j].y, a2 = v[j].z, a3 = v[j].w;
            if (a0 | a1 | a2 | a3) {
                int col0 = base + j * 256 + lane * 4;
                if (a0) { int s = atomicAdd(&cnt4[cidx], 1); te[s] = (uint16_t)col0;
                          if (a0 >> 31) atomicOr(&lneg[cidx], (int)(1u << s)); }
                if (a1) { int s = atomicAdd(&cnt4[cidx], 1); te[s] = (uint16_t)(col0 + 1);
                          if (a1 >> 31) atomicOr(&lneg[cidx], (int)(1u << s)); }
                if (a2) { int s = atomicAdd(&cnt4[cidx], 1); te[s] = (uint16_t)(col0 + 2);
                          if (a2 >> 31) atomicOr(&lneg[cidx], (int)(1u << s)); }
                if (a3) { int s = atomicAdd(&cnt4[cidx], 1); te[s] = (uint16_t)(col0 + 3);
                          if (a3 >> 31) atomicOr(&lneg[cidx], (int)(1u << s)); }
            }
        }
        __syncthreads();
        if (lane == 0) {
            // waves paired on one row (W1/W2 halves) write identical values: benign
            int cnt = cnt4[cidx];
            unsigned nb = (unsigned)lneg[cidx];
            unsigned vb = (cnt >= 32) ? 0xFFFFFFFFu : ((1u << cnt) - 1u);
            uint2 pr; pr.x = nb; pr.y = vb;
            *(uint2*)(bits + (size_t)row * 2) = pr;
        }
        return;
    }
    {
        // ---- twt: transpose+convert out_w -> wt bf16 (swizzled) ----
        int b2 = bid - 5632;
        int kt = b2 % 192, ct = b2 / 192;
        int k0 = kt * 64, c0 = ct * 64;
        {
            int rrow = t >> 4, c4 = t & 15;
            int c = c0 + c4 * 4;
            #pragma unroll
            for (int rd = 0; rd < 4; ++rd) {
                int kl = rd * 16 + rrow;
                f32x4 vv;
                if (c < CLS)
                    vv = __builtin_nontemporal_load(
                        (const f32x4*)&out_w[(size_t)(k0 + kl) * CLS + c]);
                else { vv.x = 0.0f; vv.y = 0.0f; vv.z = 0.0f; vv.w = 0.0f; }
                short* d = &tile[kl * 68 + c4 * 4];
                d[0] = (short)f2bf(vv.x); d[1] = (short)f2bf(vv.y);
                d[2] = (short)f2bf(vv.z); d[3] = (short)f2bf(vv.w);
            }
        }
        __syncthreads();
        {
            int chunk = t & 7, cl2 = t >> 3;
            #pragma unroll
            for (int rd = 0; rd < 2; ++rd) {
                int c_local = rd * 32 + cl2;
                int c = c0 + c_local;
                unsigned s8[8];
                #pragma unroll
                for (int j = 0; j < 8; ++j)
                    s8[j] = (unsigned)(unsigned short)tile[(chunk * 8 + j) * 68 + c_local];
                uint4 pk;
                pk.x = s8[0] | (s8[1] << 16);
                pk.y = s8[2] | (s8[3] << 16);
                pk.z = s8[4] | (s8[5] << 16);
                pk.w = s8[6] | (s8[7] << 16);
                *(uint4*)&wt[(size_t)c * KTOT + k0 + ((chunk ^ (c & 7)) * 8)] = pk;
            }
        }
    }
}

// ================= bit-sliced CSA unit: 64 neurons x 64 samples, one lane each =========
static __device__ __forceinline__ u64 unit_csa(
    const u64* __restrict__ prow,
    const uint16_t* __restrict__ table_l, const unsigned* __restrict__ bits_l, int n) {
    const uint4* tq = (const uint4*)(table_l + (size_t)n * 32);
    uint4 cwa[4] = {tq[0], tq[1], tq[2], tq[3]};
    uint2 bv = *(const uint2*)(bits_l + (size_t)n * 2);
    unsigned negb = bv.x, valb = bv.y;

    u64 P[4][4];
    #pragma unroll
    for (int k = 0; k < 4; ++k) {
        unsigned w0 = cwa[k].x, w1 = cwa[k].y, w2 = cwa[k].z, w3 = cwa[k].w;
        unsigned cc[8] = { w0 & 0xFFFFu, w0 >> 16, w1 & 0xFFFFu, w1 >> 16,
                           w2 & 0xFFFFu, w2 >> 16, w3 & 0xFFFFu, w3 >> 16 };
        u64 u[8];
        #pragma unroll
        for (int e = 0; e < 8; ++e) {
            int j = (k << 3) + e;
            u64 w = prow[cc[e]];
            u64 negm = 0ull - (u64)((negb >> j) & 1u);
            u64 vm   = 0ull - (u64)((valb >> j) & 1u);
            u[e] = (w ^ negm) & vm;
        }
        u64 s0, c0, s1, c1, s2, c2, b0, c3, t2, d0, b1, d1;
        { u64 t = u[0] ^ u[1]; s0 = t ^ u[2]; c0 = (u[0] & u[1]) | (u[2] & t); }
        { u64 t = u[3] ^ u[4]; s1 = t ^ u[5]; c1 = (u[3] & u[4]) | (u[5] & t); }
        s2 = u[6] ^ u[7]; c2 = u[6] & u[7];
        { u64 t = s0 ^ s1; b0 = t ^ s2; c3 = (s0 & s1) | (s2 & t); }
        { u64 t = c0 ^ c1; t2 = t ^ c2; d0 = (c0 & c1) | (c2 & t); }
        b1 = t2 ^ c3; d1 = t2 & c3;
        P[k][0] = b0; P[k][1] = b1; P[k][2] = d0 ^ d1; P[k][3] = d0 & d1;
    }
    u64 A[5], B[5], U[6];
    { u64 c;
      { u64 t = P[0][0] ^ P[1][0]; A[0] = t; c = P[0][0] & P[1][0]; }
      #pragma unroll
      for (int i = 1; i < 4; ++i) {
          u64 t = P[0][i] ^ P[1][i]; A[i] = t ^ c; c = (P[0][i] & P[1][i]) | (c & t); }
      A[4] = c; }
    { u64 c;
      { u64 t = P[2][0] ^ P[3][0]; B[0] = t; c = P[2][0] & P[3][0]; }
      #pragma unroll
      for (int i = 1; i < 4; ++i) {
          u64 t = P[2][i] ^ P[3][i]; B[i] = t ^ c; c = (P[2][i] & P[3][i]) | (c & t); }
      B[4] = c; }
    { u64 c;
      { u64 t = A[0] ^ B[0]; U[0] = t; c = A[0] & B[0]; }
      #pragma unroll
      for (int i = 1; i < 5; ++i) {
          u64 t = A[i] ^ B[i]; U[i] = t ^ c; c = (A[i] & B[i]) | (c & t); }
      U[5] = c; }
    int K = 60 - __popc(negb & valb);
    u64 c = 0;
    #pragma unroll
    for (int i = 0; i < 6; ++i) {
        u64 ki = 0ull - (u64)((K >> i) & 1);
        u64 t = U[i] ^ ki;
        c = (U[i] & ki) | (c & t);
    }
    return c;
}

// ================= kernel 2: bit-sliced layer (R1-proven: 512 x 64, global gathers) ====
__global__ void __launch_bounds__(64)
k_layer(const u64* __restrict__ prev2, int Kwords,
        const uint16_t* __restrict__ table_l, const unsigned* __restrict__ bits_l,
        u64* __restrict__ actout) {
    int unit = blockIdx.x;
    int lane = threadIdx.x;
    int g = unit >> 3, bg = unit & 7;
    int n = (g << 6) + lane;
    u64 c = unit_csa(prev2 + (size_t)bg * Kwords, table_l, bits_l, n);
    actout[(size_t)bg * HID + n] = c;
}

// ================= kernel 3: GEMM, atomic epilogue (no part, no reduce) ===============
__global__ void __launch_bounds__(256)
k_gemm_atomic(const u64* __restrict__ act2, const short* __restrict__ wt,
              float* __restrict__ out) {
    __shared__ __attribute__((aligned(16))) short As[128 * 64];
    __shared__ __attribute__((aligned(16))) short Bs[128 * 64];
    int bid = blockIdx.x;
    int mt = bid & 3, nt = (bid >> 2) & 7, ks = bid >> 5;
    int tid = threadIdx.x, lane = tid & 63;
    int wv = tid >> 6, waveM = wv & 1, waveN = wv >> 1;
    int quad = lane >> 4, cl = lane & 15;
    f32x4 acc[4][4] = {};
    const char* Bb = (const char*)(wt + (size_t)nt * 128 * KTOT + ks * KSPLIT);
    int r = tid >> 3, sub = tid & 7;
    for (int kk = 0; kk < KSPLIT; kk += 64) {
        #pragma unroll
        for (int rd = 0; rd < 4; ++rd) {
            size_t go = (size_t)(r + rd * 32) * (KTOT * 2) + kk * 2 + sub * 16;
            gld16(Bb + go, &Bs[(tid + rd * 256) * 8]);
        }
        {
            int kabs = ks * KSPLIT + kk;
            int l = kabs >> 12, nk = kabs & 4095;
            #pragma unroll
            for (int i = 0; i < 4; ++i) {
                int item = i * 256 + tid;
                int rr = item >> 3, gg = item & 7;
                const u64* w8 = act2 + ((size_t)(l * 8 + mt * 2 + (rr >> 6))) * HID + nk + gg * 8;
                int bl = rr & 63;
                unsigned sh[8];
                #pragma unroll
                for (int j = 0; j < 8; ++j)
                    sh[j] = (unsigned)((w8[j] >> bl) & 1ull) * 0x3F80u;
                uint4 pk;
                pk.x = sh[0] | (sh[1] << 16);
                pk.y = sh[2] | (sh[3] << 16);
                pk.z = sh[4] | (sh[5] << 16);
                pk.w = sh[6] | (sh[7] << 16);
                *(uint4*)&As[rr * 64 + ((gg ^ (rr & 7)) * 8)] = pk;
            }
        }
        __syncthreads();
        #pragma unroll
        for (int s = 0; s < 2; ++s) {
            int xr = ((s * 4 + quad) ^ (cl & 7)) * 8;
            bf16x8 af[4], bfr[4];
            #pragma unroll
            for (int mf = 0; mf < 4; ++mf)
                af[mf] = *(const bf16x8*)&As[(waveM * 64 + mf * 16 + cl) * 64 + xr];
            #pragma unroll
            for (int nf = 0; nf < 4; ++nf)
                bfr[nf] = *(const bf16x8*)&Bs[(waveN * 64 + nf * 16 + cl) * 64 + xr];
            #pragma unroll
            for (int mf = 0; mf < 4; ++mf)
                #pragma unroll
                for (int nf = 0; nf < 4; ++nf)
                    acc[mf][nf] = __builtin_amdgcn_mfma_f32_16x16x32_bf16(
                        af[mf], bfr[nf], acc[mf][nf], 0, 0, 0);
        }
        __syncthreads();
    }
    #pragma unroll
    for (int mf = 0; mf < 4; ++mf)
        #pragma unroll
        for (int nf = 0; nf < 4; ++nf) {
            int cp = nt * 128 + waveN * 64 + nf * 16 + cl;
            if (cp < CLS) {
                #pragma unroll
                for (int rr = 0; rr < 4; ++rr) {
                    int mg = mt * 128 + waveM * 64 + mf * 16 + quad * 4 + rr;
                    atomicAdd(&out[(size_t)mg * CLS + cp], acc[mf][nf][rr]);
                }
            }
        }
}

extern "C" void kernel_launch(void* const* d_in, const int* in_sizes, int n_in,
                              void* d_out, int out_size, void* d_ws, size_t ws_size,
                              hipStream_t stream) {
    const float* x     = (const float*)d_in[0];
    const float* W0    = (const float*)d_in[1];
    const float* W1    = (const float*)d_in[2];
    const float* W2    = (const float*)d_in[3];
    const float* out_w = (const float*)d_in[4];
    float* out = (float*)d_out;
    char* ws = (char*)d_ws;

    u64*       enc2   = (u64*)(ws + OFF_ENC2);
    u64*       act2   = (u64*)(ws + OFF_ACT2);
    uint16_t*  table  = (uint16_t*)(ws + OFF_TABLE);
    unsigned*  bits   = (unsigned*)(ws + OFF_SGN);
    short*     wt     = (short*)(ws + OFF_WT);

    hipLaunchKernelGGL(k_prep, dim3(8704), dim3(256), 0, stream,
                       x, enc2, W0, W1, W2, table, bits, out_w, wt, out);
    hipLaunchKernelGGL(k_layer, dim3(512), dim3(64), 0, stream,
                       enc2, ENC, table, bits, act2);
    hipLaunchKernelGGL(k_layer, dim3(512), dim3(64), 0, stream,
                       act2, HID, table + (size_t)HID * 32, bits + (size_t)HID * 2,
                       act2 + 8 * HID);
    hipLaunchKernelGGL(k_layer, dim3(512), dim3(64), 0, stream,
                       act2 + 8 * HID, HID, table + (size_t)2 * HID * 32,
                       bits + (size_t)2 * HID * 2, act2 + 16 * HID);
    hipLaunchKernelGGL(k_gemm_atomic, dim3(512), dim3(256), 0, stream,
                       act2, wt, out);
}

// Round 6
// 270.381 us; speedup vs baseline: 1.5659x; 1.0031x over previous
//
#include <hip/hip_runtime.h>
#include <stdint.h>

typedef unsigned long long u64;
typedef __attribute__((ext_vector_type(8))) short bf16x8;
typedef __attribute__((ext_vector_type(4))) float f32x4;
typedef __attribute__((ext_vector_type(4))) unsigned u32x4;

#define BATCH 512
#define FEAT 256
#define ENC 2048
#define HID 4096
#define CLS 1000
#define KTOT 12288      // 3 * 4096
#define KSPLIT 768

// ws offsets
#define OFF_ENC2   0
#define OFF_ACT2   131072
#define OFF_TABLE  917504
#define OFF_SGN    1703936      // {negbits,validbits} u32 pairs per neuron
#define OFF_WT     2097152

// ---------- fp32 -> bf16 RNE ----------
static __device__ inline unsigned short f2bf(float f) {
    unsigned u = __float_as_uint(f);
    return (unsigned short)((u + 0x7FFFu + ((u >> 16) & 1u)) >> 16);
}

// ---------- async global->LDS, 16B/lane ----------
static __device__ inline void gld16(const void* g, void* s) {
    __builtin_amdgcn_global_load_lds((const __attribute__((address_space(1))) void*)g,
                                     (__attribute__((address_space(3))) void*)s, 16, 0, 0);
}

// ================= kernel 1: fused prep = encode+zero | scan | twt =================
// blocks [0,512): encode + zero out   [512,3584): scan (1 wave = 1 row)   [3584,6656): twt
__global__ void __launch_bounds__(256)
k_prep(const float* __restrict__ x, u64* __restrict__ enc2,
       const float* __restrict__ W0, const float* __restrict__ W1,
       const float* __restrict__ W2,
       uint16_t* __restrict__ table, unsigned* __restrict__ bits,
       const float* __restrict__ out_w, short* __restrict__ wt,
       float* __restrict__ out) {
    __shared__ short tile[64 * 68];
    int bid = blockIdx.x;
    int t = threadIdx.x;
    int lane = t & 63;
    int wv = t >> 6;

    if (bid < 512) {
        // zero out (512*256 float4 slots cover the 128000 needed)
        int oidx = bid * 256 + t;
        if (oidx < (BATCH * CLS) / 4) {
            f32x4 z = {0.f, 0.f, 0.f, 0.f};
            *(f32x4*)&out[(size_t)oidx * 4] = z;
        }
        int wid = bid * 4 + wv;
        int f = wid >> 3, bg = wid & 7;
        float v = x[(size_t)(bg * 64 + lane) * FEAT + f];
        v = fminf(fmaxf(v, 0.0f), 1.0f);
        int lev = (int)rintf(v * 255.0f);                // RNE == jnp.round
        unsigned gray = (unsigned)(lev ^ (lev >> 1));
        u64 w = 0;
        #pragma unroll
        for (int bit = 0; bit < 8; ++bit) {
            u64 m = __ballot((gray >> bit) & 1u);
            if (lane == bit) w = m;
        }
        if (lane < 8) enc2[(size_t)bg * ENC + f * 8 + lane] = w;
        return;
    }
    if (bid < 3584) {
        // ---- scan: 1 wave = 1 weight row; ballot+prefix slot assignment (no atomics) --
        int row = (bid - 512) * 4 + wv;
        const float* Wr; int npass;
        if (row < HID)          { Wr = W0 + (size_t)row * ENC;             npass = 1; }
        else if (row < 2 * HID) { Wr = W1 + (size_t)(row - HID) * HID;     npass = 2; }
        else                    { Wr = W2 + (size_t)(row - 2 * HID) * HID; npass = 2; }
        uint16_t* te = table + (size_t)row * 32;
        unsigned cnt = 0, mynegs = 0;
        u64 ltmask = (1ull << lane) - 1ull;
        for (int p = 0; p < npass; ++p) {
            const u32x4* p4 = (const u32x4*)Wr + p * 512 + lane;
            u32x4 v[8];
            #pragma unroll
            for (int j = 0; j < 8; ++j) v[j] = __builtin_nontemporal_load(p4 + j * 64);
            #pragma unroll
            for (int j = 0; j < 8; ++j) {
                int col0 = (p * 8 + j) * 256 + lane * 4;
                unsigned aa[4] = {v[j].x, v[j].y, v[j].z, v[j].w};
                #pragma unroll
                for (int c = 0; c < 4; ++c) {
                    unsigned a = aa[c];
                    u64 m = __ballot(a != 0u);
                    if (a) {
                        int slot = (int)cnt + (int)__popcll(m & ltmask);
                        te[slot] = (uint16_t)(col0 + c);
                        if (a >> 31) mynegs |= 1u << slot;
                    }
                    cnt += (unsigned)__popcll(m);
                }
            }
        }
        // wave OR-reduce of negbits
        #pragma unroll
        for (int off = 32; off; off >>= 1) mynegs |= __shfl_xor(mynegs, off);
        // tail-pad unused slots (disjoint addresses from the scatter -> no ordering hazard)
        if (lane >= (int)cnt && lane < 32) te[lane] = 0;
        if (lane == 0) {
            uint2 pr;
            pr.x = mynegs;
            pr.y = (cnt >= 32) ? 0xFFFFFFFFu : ((1u << cnt) - 1u);
            *(uint2*)(bits + (size_t)row * 2) = pr;
        }
        return;
    }
    {
        // ---- twt: transpose+convert out_w -> wt bf16 (swizzled) ----
        int b2 = bid - 3584;
        int kt = b2 % 192, ct = b2 / 192;
        int k0 = kt * 64, c0 = ct * 64;
        {
            int rrow = t >> 4, c4 = t & 15;
            int c = c0 + c4 * 4;
            #pragma unroll
            for (int rd = 0; rd < 4; ++rd) {
                int kl = rd * 16 + rrow;
                f32x4 vv;
                if (c < CLS)
                    vv = __builtin_nontemporal_load(
                        (const f32x4*)&out_w[(size_t)(k0 + kl) * CLS + c]);
                else { vv.x = 0.0f; vv.y = 0.0f; vv.z = 0.0f; vv.w = 0.0f; }
                short* d = &tile[kl * 68 + c4 * 4];
                d[0] = (short)f2bf(vv.x); d[1] = (short)f2bf(vv.y);
                d[2] = (short)f2bf(vv.z); d[3] = (short)f2bf(vv.w);
            }
        }
        __syncthreads();
        {
            int chunk = t & 7, cl2 = t >> 3;
            #pragma unroll
            for (int rd = 0; rd < 2; ++rd) {
                int c_local = rd * 32 + cl2;
                int c = c0 + c_local;
                unsigned s8[8];
                #pragma unroll
                for (int j = 0; j < 8; ++j)
                    s8[j] = (unsigned)(unsigned short)tile[(chunk * 8 + j) * 68 + c_local];
                uint4 pk;
                pk.x = s8[0] | (s8[1] << 16);
                pk.y = s8[2] | (s8[3] << 16);
                pk.z = s8[4] | (s8[5] << 16);
                pk.w = s8[6] | (s8[7] << 16);
                *(uint4*)&wt[(size_t)c * KTOT + k0 + ((chunk ^ (c & 7)) * 8)] = pk;
            }
        }
    }
}

// ================= bit-sliced CSA unit: 64 neurons x 64 samples, one lane each =========
static __device__ __forceinline__ u64 unit_csa(
    const u64* __restrict__ prow,
    const uint16_t* __restrict__ table_l, const unsigned* __restrict__ bits_l, int n) {
    const uint4* tq = (const uint4*)(table_l + (size_t)n * 32);
    uint4 cwa[4] = {tq[0], tq[1], tq[2], tq[3]};
    uint2 bv = *(const uint2*)(bits_l + (size_t)n * 2);
    unsigned negb = bv.x, valb = bv.y;

    u64 P[4][4];
    #pragma unroll
    for (int k = 0; k < 4; ++k) {
        unsigned w0 = cwa[k].x, w1 = cwa[k].y, w2 = cwa[k].z, w3 = cwa[k].w;
        unsigned cc[8] = { w0 & 0xFFFFu, w0 >> 16, w1 & 0xFFFFu, w1 >> 16,
                           w2 & 0xFFFFu, w2 >> 16, w3 & 0xFFFFu, w3 >> 16 };
        u64 u[8];
        #pragma unroll
        for (int e = 0; e < 8; ++e) {
            int j = (k << 3) + e;
            u64 w = prow[cc[e]];
            u64 negm = 0ull - (u64)((negb >> j) & 1u);
            u64 vm   = 0ull - (u64)((valb >> j) & 1u);
            u[e] = (w ^ negm) & vm;
        }
        u64 s0, c0, s1, c1, s2, c2, b0, c3, t2, d0, b1, d1;
        { u64 t = u[0] ^ u[1]; s0 = t ^ u[2]; c0 = (u[0] & u[1]) | (u[2] & t); }
        { u64 t = u[3] ^ u[4]; s1 = t ^ u[5]; c1 = (u[3] & u[4]) | (u[5] & t); }
        s2 = u[6] ^ u[7]; c2 = u[6] & u[7];
        { u64 t = s0 ^ s1; b0 = t ^ s2; c3 = (s0 & s1) | (s2 & t); }
        { u64 t = c0 ^ c1; t2 = t ^ c2; d0 = (c0 & c1) | (c2 & t); }
        b1 = t2 ^ c3; d1 = t2 & c3;
        P[k][0] = b0; P[k][1] = b1; P[k][2] = d0 ^ d1; P[k][3] = d0 & d1;
    }
    u64 A[5], B[5], U[6];
    { u64 c;
      { u64 t = P[0][0] ^ P[1][0]; A[0] = t; c = P[0][0] & P[1][0]; }
      #pragma unroll
      for (int i = 1; i < 4; ++i) {
          u64 t = P[0][i] ^ P[1][i]; A[i] = t ^ c; c = (P[0][i] & P[1][i]) | (c & t); }
      A[4] = c; }
    { u64 c;
      { u64 t = P[2][0] ^ P[3][0]; B[0] = t; c = P[2][0] & P[3][0]; }
      #pragma unroll
      for (int i = 1; i < 4; ++i) {
          u64 t = P[2][i] ^ P[3][i]; B[i] = t ^ c; c = (P[2][i] & P[3][i]) | (c & t); }
      B[4] = c; }
    { u64 c;
      { u64 t = A[0] ^ B[0]; U[0] = t; c = A[0] & B[0]; }
      #pragma unroll
      for (int i = 1; i < 5; ++i) {
          u64 t = A[i] ^ B[i]; U[i] = t ^ c; c = (A[i] & B[i]) | (c & t); }
      U[5] = c; }
    int K = 60 - __popc(negb & valb);
    u64 c = 0;
    #pragma unroll
    for (int i = 0; i < 6; ++i) {
        u64 ki = 0ull - (u64)((K >> i) & 1);
        u64 t = U[i] ^ ki;
        c = (U[i] & ki) | (c & t);
    }
    return c;
}

// ================= kernel 2: bit-sliced layer (R1-proven: 512 x 64, global gathers) ====
__global__ void __launch_bounds__(64)
k_layer(const u64* __restrict__ prev2, int Kwords,
        const uint16_t* __restrict__ table_l, const unsigned* __restrict__ bits_l,
        u64* __restrict__ actout) {
    int unit = blockIdx.x;
    int lane = threadIdx.x;
    int g = unit >> 3, bg = unit & 7;
    int n = (g << 6) + lane;
    u64 c = unit_csa(prev2 + (size_t)bg * Kwords, table_l, bits_l, n);
    actout[(size_t)bg * HID + n] = c;
}

// ================= kernel 3: GEMM, M-tile=64 (bg-aligned), XCD-pinned nt ==============
// grid 1024 = 8 mt x 8 nt x 16 ks; nt = bid&7 -> all blocks sharing a wt panel on one
// XCD's L2. 4 blocks/CU co-resident (24 KB LDS). Atomic epilogue into out.
__global__ void __launch_bounds__(256)
k_gemm_atomic(const u64* __restrict__ act2, const short* __restrict__ wt,
              float* __restrict__ out) {
    __shared__ __attribute__((aligned(16))) short As[64 * 64];
    __shared__ __attribute__((aligned(16))) short Bs[128 * 64];
    int bid = blockIdx.x;
    int nt = bid & 7, ks = (bid >> 3) & 15, mt = bid >> 7;
    int tid = threadIdx.x, lane = tid & 63;
    int wv = tid >> 6;
    int quad = lane >> 4, cl = lane & 15;
    f32x4 acc[4][2] = {};
    const char* Bb = (const char*)(wt + (size_t)nt * 128 * KTOT + ks * KSPLIT);
    int r = tid >> 3, sub = tid & 7;
    for (int kk = 0; kk < KSPLIT; kk += 64) {
        #pragma unroll
        for (int rd = 0; rd < 4; ++rd) {
            size_t go = (size_t)(r + rd * 32) * (KTOT * 2) + kk * 2 + sub * 16;
            gld16(Bb + go, &Bs[(tid + rd * 256) * 8]);
        }
        {
            int kabs = ks * KSPLIT + kk;
            int l = kabs >> 12, nk = kabs & 4095;
            #pragma unroll
            for (int i = 0; i < 2; ++i) {
                int item = i * 256 + tid;
                int rr = item >> 3, gg = item & 7;
                const u64* w8 = act2 + ((size_t)(l * 8 + mt)) * HID + nk + gg * 8;
                unsigned sh[8];
                #pragma unroll
                for (int j = 0; j < 8; ++j)
                    sh[j] = (unsigned)((w8[j] >> rr) & 1ull) * 0x3F80u;
                uint4 pk;
                pk.x = sh[0] | (sh[1] << 16);
                pk.y = sh[2] | (sh[3] << 16);
                pk.z = sh[4] | (sh[5] << 16);
                pk.w = sh[6] | (sh[7] << 16);
                *(uint4*)&As[rr * 64 + ((gg ^ (rr & 7)) * 8)] = pk;
            }
        }
        __syncthreads();
        #pragma unroll
        for (int s = 0; s < 2; ++s) {
            int xr = ((s * 4 + quad) ^ (cl & 7)) * 8;
            bf16x8 af[4], bfr[2];
            #pragma unroll
            for (int mf = 0; mf < 4; ++mf)
                af[mf] = *(const bf16x8*)&As[(mf * 16 + cl) * 64 + xr];
            #pragma unroll
            for (int nf = 0; nf < 2; ++nf)
                bfr[nf] = *(const bf16x8*)&Bs[(wv * 32 + nf * 16 + cl) * 64 + xr];
            #pragma unroll
            for (int mf = 0; mf < 4; ++mf)
                #pragma unroll
                for (int nf = 0; nf < 2; ++nf)
                    acc[mf][nf] = __builtin_amdgcn_mfma_f32_16x16x32_bf16(
                        af[mf], bfr[nf], acc[mf][nf], 0, 0, 0);
        }
        __syncthreads();
    }
    #pragma unroll
    for (int mf = 0; mf < 4; ++mf)
        #pragma unroll
        for (int nf = 0; nf < 2; ++nf) {
            int cp = nt * 128 + wv * 32 + nf * 16 + cl;
            if (cp < CLS) {
                #pragma unroll
                for (int rr = 0; rr < 4; ++rr) {
                    int mg = mt * 64 + mf * 16 + quad * 4 + rr;
                    atomicAdd(&out[(size_t)mg * CLS + cp], acc[mf][nf][rr]);
                }
            }
        }
}

extern "C" void kernel_launch(void* const* d_in, const int* in_sizes, int n_in,
                              void* d_out, int out_size, void* d_ws, size_t ws_size,
                              hipStream_t stream) {
    const float* x     = (const float*)d_in[0];
    const float* W0    = (const float*)d_in[1];
    const float* W1    = (const float*)d_in[2];
    const float* W2    = (const float*)d_in[3];
    const float* out_w = (const float*)d_in[4];
    float* out = (float*)d_out;
    char* ws = (char*)d_ws;

    u64*       enc2   = (u64*)(ws + OFF_ENC2);
    u64*       act2   = (u64*)(ws + OFF_ACT2);
    uint16_t*  table  = (uint16_t*)(ws + OFF_TABLE);
    unsigned*  bits   = (unsigned*)(ws + OFF_SGN);
    short*     wt     = (short*)(ws + OFF_WT);

    hipLaunchKernelGGL(k_prep, dim3(6656), dim3(256), 0, stream,
                       x, enc2, W0, W1, W2, table, bits, out_w, wt, out);
    hipLaunchKernelGGL(k_layer, dim3(512), dim3(64), 0, stream,
                       enc2, ENC, table, bits, act2);
    hipLaunchKernelGGL(k_layer, dim3(512), dim3(64), 0, stream,
                       act2, HID, table + (size_t)HID * 32, bits + (size_t)HID * 2,
                       act2 + 8 * HID);
    hipLaunchKernelGGL(k_layer, dim3(512), dim3(64), 0, stream,
                       act2 + 8 * HID, HID, table + (size_t)2 * HID * 32,
                       bits + (size_t)2 * HID * 2, act2 + 16 * HID);
    hipLaunchKernelGGL(k_gemm_atomic, dim3(1024), dim3(256), 0, stream,
                       act2, wt, out);
}